// Round 1
// baseline (50812.024 us; speedup 1.0000x reference)
//
#include <hip/hip_runtime.h>
#include <stdint.h>

typedef unsigned short u16;
typedef unsigned int u32;

#define TT 1024
#define BB 64
#define EE 256
#define HH 512
#define GG 2048   // 4H
#define NWG 128   // scan workgroups, 4 h-units each

__device__ __forceinline__ float bf2f(u16 h) {
  union { u32 i; float f; } v; v.i = ((u32)h) << 16; return v.f;
}
__device__ __forceinline__ float bf2f_lo(u32 p) {
  union { u32 i; float f; } v; v.i = p << 16; return v.f;
}
__device__ __forceinline__ float bf2f_hi(u32 p) {
  union { u32 i; float f; } v; v.i = p & 0xffff0000u; return v.f;
}
__device__ __forceinline__ u16 f2bf(float f) {
  union { float f; u32 i; } v; v.f = f;
  u32 b = v.i;
  return (u16)((b + 0x7fffu + ((b >> 16) & 1u)) >> 16);
}

// ---------------------------------------------------------------------------
// Kernel 1: xz[t][col][b] (bf16) = (emb[x[b,t]] @ kernel)[col] + bias[col]
// grid (T, 32), block 256. Tile: M=64 (all b at fixed t), N=64 cols, K=256.
// ---------------------------------------------------------------------------
__global__ __launch_bounds__(256) void xz_gemm(
    const int* __restrict__ x, const float* __restrict__ emb,
    const float* __restrict__ Wk, const float* __restrict__ bias,
    u16* __restrict__ xz) {
  __shared__ float Ash[64 * 68];   // [64 b][64 k] padded
  __shared__ float Bsh[64 * 64];   // [64 k][64 col]
  __shared__ u16 Csh[64 * 64];     // [col][b] bf16 staging for coalesced store
  __shared__ int xidx[64];
  const int tid = threadIdx.x;
  const int t = blockIdx.x;
  const int colBase = blockIdx.y * 64;
  if (tid < 64) xidx[tid] = x[(size_t)tid * TT + t];
  __syncthreads();
  const int tx4 = (tid & 15) * 4;
  const int ty4 = (tid >> 4) * 4;
  const int rr = tid >> 6;   // 0..3
  const int cc = tid & 63;   // 0..63
  float acc[4][4] = {};
  for (int kc = 0; kc < EE; kc += 64) {
#pragma unroll
    for (int it = 0; it < 16; ++it) {
      int row = rr + it * 4;
      Ash[row * 68 + cc] = emb[(size_t)xidx[row] * EE + kc + cc];
    }
#pragma unroll
    for (int it = 0; it < 16; ++it) {
      int krow = rr + it * 4;
      Bsh[krow * 64 + cc] = Wk[(size_t)(kc + krow) * GG + colBase + cc];
    }
    __syncthreads();
#pragma unroll
    for (int kk = 0; kk < 64; kk += 4) {
      float4 b0 = *(const float4*)&Bsh[(kk + 0) * 64 + tx4];
      float4 b1 = *(const float4*)&Bsh[(kk + 1) * 64 + tx4];
      float4 b2 = *(const float4*)&Bsh[(kk + 2) * 64 + tx4];
      float4 b3 = *(const float4*)&Bsh[(kk + 3) * 64 + tx4];
#pragma unroll
      for (int i = 0; i < 4; ++i) {
        float4 av = *(const float4*)&Ash[(ty4 + i) * 68 + kk];
        acc[i][0] += av.x * b0.x + av.y * b1.x + av.z * b2.x + av.w * b3.x;
        acc[i][1] += av.x * b0.y + av.y * b1.y + av.z * b2.y + av.w * b3.y;
        acc[i][2] += av.x * b0.z + av.y * b1.z + av.z * b2.z + av.w * b3.z;
        acc[i][3] += av.x * b0.w + av.y * b1.w + av.z * b2.w + av.w * b3.w;
      }
    }
    __syncthreads();
  }
#pragma unroll
  for (int j = 0; j < 4; ++j) {
    float bj = bias[colBase + tx4 + j];
#pragma unroll
    for (int i = 0; i < 4; ++i) {
      Csh[(tx4 + j) * 64 + (ty4 + i)] = f2bf(acc[i][j] + bj);
    }
  }
  __syncthreads();
  u32* dst = (u32*)(xz + ((size_t)t * GG + colBase) * BB);
  const u32* src = (const u32*)Csh;
  for (int i = tid; i < 64 * 32; i += 256) dst[i] = src[i];
}

// ---------------------------------------------------------------------------
// Kernel 2: persistent LSTM scan. 128 WGs x 256 threads; WG w owns h-units
// [4w, 4w+4). rec_kernel slice (16 cols x 512 k, f32) lives in LDS for the
// whole kernel. h broadcast via double-buffered global bf16 [b][u] + flags.
// thread: b = tid&63 (lane), ul = tid>>6 (wave) -> unit u = 4w+ul.
// ---------------------------------------------------------------------------
__global__ __launch_bounds__(256) void lstm_scan(
    const int* __restrict__ x, const float* __restrict__ h0,
    const float* __restrict__ c0, const float* __restrict__ rec,
    const u16* __restrict__ xz, float* __restrict__ out,
    u16* __restrict__ hb0, u16* __restrict__ hb1,
    u32* __restrict__ flags) {
  extern __shared__ char smem[];
  u16* h_lds = (u16*)smem;                        // [64 b][520] bf16 (pad 8)
  float* W_lds = (float*)(smem + 64 * 520 * 2);   // [16 lc][512 k], lc=g*4+uu
  const int tid = threadIdx.x;
  const int w = blockIdx.x;
  const int U0 = w * 4;
  const int b = tid & 63;
  const int ul = tid >> 6;
  const int u = U0 + ul;

  // Stage W slice (once). lc = g*4+uu -> global col g*512 + U0 + uu.
  for (int i = tid; i < 16 * 512; i += 256) {
    int lc = i >> 9, k = i & 511;
    int g = lc >> 2, uu = lc & 3;
    W_lds[i] = rec[(size_t)k * GG + g * HH + U0 + uu];
  }
  // Stage h0 (f32 global [b][k]) -> bf16 LDS [b][k].
  for (int i = tid; i < 64 * 512; i += 256) {
    int bb = i >> 9, kk = i & 511;
    h_lds[bb * 520 + kk] = f2bf(h0[i]);
  }
  float c_reg = c0[(size_t)b * HH + u];
  __syncthreads();

  const float* W0 = &W_lds[(0 + ul) * 512];
  const float* W1 = &W_lds[(4 + ul) * 512];
  const float* W2 = &W_lds[(8 + ul) * 512];
  const float* W3 = &W_lds[(12 + ul) * 512];
  const u16* hrow = &h_lds[b * 520];

  for (int t = 0; t < TT; ++t) {
    // Early loads (latency hidden under the K loop).
    const size_t xzb = ((size_t)t * GG + u) * BB + b;
    float xzv0 = bf2f(xz[xzb + (size_t)0 * HH * BB]);
    float xzv1 = bf2f(xz[xzb + (size_t)1 * HH * BB]);
    float xzv2 = bf2f(xz[xzb + (size_t)2 * HH * BB]);
    float xzv3 = bf2f(xz[xzb + (size_t)3 * HH * BB]);
    const bool m = (x[(size_t)b * TT + t] != 0);
    const float hp = bf2f(hrow[u]);

    float za0 = 0.f, za1 = 0.f, za2 = 0.f, za3 = 0.f;
#pragma unroll 4
    for (int k0 = 0; k0 < 512; k0 += 8) {
      uint4 hv = *(const uint4*)&hrow[k0];
      float hf0 = bf2f_lo(hv.x), hf1 = bf2f_hi(hv.x);
      float hf2 = bf2f_lo(hv.y), hf3 = bf2f_hi(hv.y);
      float hf4 = bf2f_lo(hv.z), hf5 = bf2f_hi(hv.z);
      float hf6 = bf2f_lo(hv.w), hf7 = bf2f_hi(hv.w);
      {
        float4 wa = *(const float4*)&W0[k0];
        float4 wb = *(const float4*)&W0[k0 + 4];
        za0 += hf0 * wa.x + hf1 * wa.y + hf2 * wa.z + hf3 * wa.w
             + hf4 * wb.x + hf5 * wb.y + hf6 * wb.z + hf7 * wb.w;
      }
      {
        float4 wa = *(const float4*)&W1[k0];
        float4 wb = *(const float4*)&W1[k0 + 4];
        za1 += hf0 * wa.x + hf1 * wa.y + hf2 * wa.z + hf3 * wa.w
             + hf4 * wb.x + hf5 * wb.y + hf6 * wb.z + hf7 * wb.w;
      }
      {
        float4 wa = *(const float4*)&W2[k0];
        float4 wb = *(const float4*)&W2[k0 + 4];
        za2 += hf0 * wa.x + hf1 * wa.y + hf2 * wa.z + hf3 * wa.w
             + hf4 * wb.x + hf5 * wb.y + hf6 * wb.z + hf7 * wb.w;
      }
      {
        float4 wa = *(const float4*)&W3[k0];
        float4 wb = *(const float4*)&W3[k0 + 4];
        za3 += hf0 * wa.x + hf1 * wa.y + hf2 * wa.z + hf3 * wa.w
             + hf4 * wb.x + hf5 * wb.y + hf6 * wb.z + hf7 * wb.w;
      }
    }
    float z0 = za0 + xzv0;
    float z1 = za1 + xzv1;
    float z2 = za2 + xzv2;
    float z3 = za3 + xzv3;
    float ig = 1.f / (1.f + __expf(-z0));
    float fg = 1.f / (1.f + __expf(-z1));
    float gg = tanhf(z2);
    float og = 1.f / (1.f + __expf(-z3));
    float cn = fg * c_reg + ig * gg;
    float hn = og * tanhf(cn);
    float ho = m ? hn : hp;
    c_reg = m ? cn : c_reg;
    u16 hbv = f2bf(ho);
    u16* hdst = (t & 1) ? hb1 : hb0;
    hdst[(size_t)b * HH + u] = hbv;
    out[((size_t)b * TT + t) * HH + u] = bf2f(hbv);
    if (t == TT - 1) {
      out[(size_t)BB * TT * HH + (size_t)b * HH + u] = bf2f(hbv);
      out[(size_t)BB * TT * HH + (size_t)BB * HH + (size_t)b * HH + u] = c_reg;
      break;
    }
    // Publish: all h writes drained (syncthreads) then release-store flag.
    __syncthreads();
    if (tid == 0)
      __hip_atomic_store(&flags[w * 16], (u32)(t + 1), __ATOMIC_RELEASE,
                         __HIP_MEMORY_SCOPE_AGENT);
    // Wait for all 128 WGs (acquire loads: refresh caches every poll).
    {
      const u32 tgt = (u32)(t + 1);
      const int l = tid & 63;
      while (true) {
        u32 f1 = __hip_atomic_load(&flags[l * 16], __ATOMIC_ACQUIRE,
                                   __HIP_MEMORY_SCOPE_AGENT);
        u32 f2 = __hip_atomic_load(&flags[(l + 64) * 16], __ATOMIC_ACQUIRE,
                                   __HIP_MEMORY_SCOPE_AGENT);
        if (__all((f1 >= tgt) && (f2 >= tgt))) break;
        __builtin_amdgcn_s_sleep(8);
      }
    }
    __threadfence();
    // Restage h for next step from hbuf[t&1] (global bf16 [b][u]).
    {
      const u16* hsrc = (t & 1) ? hb1 : hb0;
      const u32* hs32 = (const u32*)hsrc;
      for (int i = tid; i < 64 * 256; i += 256) {
        u32 v = hs32[i];
        int bb = i >> 8, kk = (i & 255) * 2;
        *(u32*)&h_lds[bb * 520 + kk] = v;
      }
    }
    __syncthreads();
  }
}

// ---------------------------------------------------------------------------
extern "C" void kernel_launch(void* const* d_in, const int* in_sizes, int n_in,
                              void* d_out, int out_size, void* d_ws,
                              size_t ws_size, hipStream_t stream) {
  const int* x = (const int*)d_in[0];
  const float* h0 = (const float*)d_in[1];
  const float* c0 = (const float*)d_in[2];
  const float* emb = (const float*)d_in[3];
  const float* Wk = (const float*)d_in[4];
  const float* rec = (const float*)d_in[5];
  const float* bias = (const float*)d_in[6];
  float* out = (float*)d_out;
  char* ws = (char*)d_ws;

  const size_t xz_bytes = (size_t)TT * GG * BB * 2;  // 256 MiB bf16
  u16* xz = (u16*)ws;
  u16* hb0 = (u16*)(ws + xz_bytes);
  u16* hb1 = (u16*)(ws + xz_bytes + 65536);
  u32* flags = (u32*)(ws + xz_bytes + 131072);
  if (ws_size < xz_bytes + 131072 + 8192) return;  // ws too small: visible fail

  hipMemsetAsync(flags, 0, 8192, stream);

  dim3 g1(TT, 32);
  xz_gemm<<<g1, 256, 0, stream>>>(x, emb, Wk, bias, xz);

  const int smem2 = 64 * 520 * 2 + 16 * 512 * 4;  // 99328 B
  hipFuncSetAttribute((const void*)lstm_scan,
                      hipFuncAttributeMaxDynamicSharedMemorySize, smem2);
  lstm_scan<<<NWG, 256, smem2, stream>>>(x, h0, c0, rec, xz, out, hb0, hb1,
                                         flags);
}

// Round 2
// 12733.741 us; speedup vs baseline: 3.9903x; 3.9903x over previous
//
#include <hip/hip_runtime.h>
#include <stdint.h>

typedef unsigned short u16;
typedef unsigned int u32;
typedef __attribute__((ext_vector_type(8))) short bf16x8;
typedef __attribute__((ext_vector_type(4))) float f32x4;

#define TT 1024
#define BB 64
#define EE 256
#define HH 512
#define GG 2048   // 4H
#define NWG 32    // scan workgroups, 16 h-units each

__device__ __forceinline__ float bf2f(u16 h) {
  union { u32 i; float f; } v; v.i = ((u32)h) << 16; return v.f;
}
__device__ __forceinline__ u16 f2bf(float f) {
  union { float f; u32 i; } v; v.f = f;
  u32 b = v.i;
  return (u16)((b + 0x7fffu + ((b >> 16) & 1u)) >> 16);
}
__device__ __forceinline__ float sigm(float x) {
  return 1.f / (1.f + __expf(-x));
}
__device__ __forceinline__ float tanhfast(float x) {
  float e = __expf(2.f * x);
  return 1.f - 2.f / (e + 1.f);
}

// ---------------------------------------------------------------------------
// Kernel 1: xz[t][col][b] (bf16) = (emb[x[b,t]] @ kernel)[col] + bias[col]
// (unchanged from round 1 — proven correct; optimize later if it dominates)
// ---------------------------------------------------------------------------
__global__ __launch_bounds__(256) void xz_gemm(
    const int* __restrict__ x, const float* __restrict__ emb,
    const float* __restrict__ Wk, const float* __restrict__ bias,
    u16* __restrict__ xz) {
  __shared__ float Ash[64 * 68];
  __shared__ float Bsh[64 * 64];
  __shared__ u16 Csh[64 * 64];
  __shared__ int xidx[64];
  const int tid = threadIdx.x;
  const int t = blockIdx.x;
  const int colBase = blockIdx.y * 64;
  if (tid < 64) xidx[tid] = x[(size_t)tid * TT + t];
  __syncthreads();
  const int tx4 = (tid & 15) * 4;
  const int ty4 = (tid >> 4) * 4;
  const int rr = tid >> 6;
  const int cc = tid & 63;
  float acc[4][4] = {};
  for (int kc = 0; kc < EE; kc += 64) {
#pragma unroll
    for (int it = 0; it < 16; ++it) {
      int row = rr + it * 4;
      Ash[row * 68 + cc] = emb[(size_t)xidx[row] * EE + kc + cc];
    }
#pragma unroll
    for (int it = 0; it < 16; ++it) {
      int krow = rr + it * 4;
      Bsh[krow * 64 + cc] = Wk[(size_t)(kc + krow) * GG + colBase + cc];
    }
    __syncthreads();
#pragma unroll
    for (int kk = 0; kk < 64; kk += 4) {
      float4 b0 = *(const float4*)&Bsh[(kk + 0) * 64 + tx4];
      float4 b1 = *(const float4*)&Bsh[(kk + 1) * 64 + tx4];
      float4 b2 = *(const float4*)&Bsh[(kk + 2) * 64 + tx4];
      float4 b3 = *(const float4*)&Bsh[(kk + 3) * 64 + tx4];
#pragma unroll
      for (int i = 0; i < 4; ++i) {
        float4 av = *(const float4*)&Ash[(ty4 + i) * 68 + kk];
        acc[i][0] += av.x * b0.x + av.y * b1.x + av.z * b2.x + av.w * b3.x;
        acc[i][1] += av.x * b0.y + av.y * b1.y + av.z * b2.y + av.w * b3.y;
        acc[i][2] += av.x * b0.z + av.y * b1.z + av.z * b2.z + av.w * b3.z;
        acc[i][3] += av.x * b0.w + av.y * b1.w + av.z * b2.w + av.w * b3.w;
      }
    }
    __syncthreads();
  }
#pragma unroll
  for (int j = 0; j < 4; ++j) {
    float bj = bias[colBase + tx4 + j];
#pragma unroll
    for (int i = 0; i < 4; ++i) {
      Csh[(tx4 + j) * 64 + (ty4 + i)] = f2bf(acc[i][j] + bj);
    }
  }
  __syncthreads();
  u32* dst = (u32*)(xz + ((size_t)t * GG + colBase) * BB);
  const u32* src = (const u32*)Csh;
  for (int i = tid; i < 64 * 32; i += 256) dst[i] = src[i];
}

// ---------------------------------------------------------------------------
// Kernel 2: persistent MFMA LSTM scan. 32 WGs x 512 threads (8 waves).
// WG w owns h-units [16w,16w+16) = 64 gate-cols. R slice held in VGPRs as
// MFMA B-fragments (loaded once). h exchanged via 64KB global buffers in
// MFMA A-fragment order (double-buffered) + per-WG flags.
// Wave wv: mt = wv&3 (batch tile), ntp = wv>>2 -> tiles nt = 2*ntp+{0,1}.
// Col map: col(nt, n=l&15) = (n&3)*512 + U0 + nt*4 + (n>>2)  (gate = n&3).
// After MFMA: 4x4 transpose across lane groups so lane (tag q=l&3) holds all
// 4 gates of batch row r=q; each lane finishes exactly 2 (b,u) cells.
// ---------------------------------------------------------------------------
__global__ __launch_bounds__(512, 2) void lstm_scan2(
    const int* __restrict__ x, const float* __restrict__ h0,
    const float* __restrict__ c0, const float* __restrict__ rec,
    const u16* __restrict__ xz, float* __restrict__ out,
    u16* __restrict__ hb0, u16* __restrict__ hb1, u32* __restrict__ flags) {
  __shared__ u32 xmask[64][32];
  const int tid = threadIdx.x;
  const int wv = tid >> 6;
  const int l = tid & 63;
  const int w = blockIdx.x;
  const int U0 = w * 16;
  const int mt = wv & 3;
  const int ntp = wv >> 2;
  const int q = l & 3;
  const int b = mt * 16 + ((l >> 4) << 2) + q;
  const int uoff = (l >> 2) & 3;
  const int u0g = U0 + (2 * ntp + 0) * 4 + uoff;
  const int u1g = U0 + (2 * ntp + 1) * 4 + uoff;
  const int col0 = q * 512 + u0g;
  const int col1 = q * 512 + u1g;

  // --- B fragments (R slice) into registers, once. k = ks*32+(l>>4)*8+j. ---
  bf16x8 bfr0[16], bfr1[16];
#pragma unroll
  for (int ks = 0; ks < 16; ++ks) {
    int kbase = ks * 32 + ((l >> 4) << 3);
#pragma unroll
    for (int j = 0; j < 8; ++j) {
      bfr0[ks][j] = (short)f2bf(rec[(size_t)(kbase + j) * GG + col0]);
      bfr1[ks][j] = (short)f2bf(rec[(size_t)(kbase + j) * GG + col1]);
    }
  }

  // --- stage h0 into hb0 (A-fragment order), build x bitmask in LDS ---
  for (int i = tid; i < 1024; i += 512) {
    int uu = i >> 6, b2 = i & 63;
    int u = U0 + uu;
    u16 v = f2bf(h0[(size_t)b2 * HH + u]);
    int ln = (b2 & 15) | (((u >> 3) & 3) << 4);
    hb0[(size_t)(((b2 >> 4) * 16 + (u >> 5)) * 64 + ln) * 8 + (u & 7)] = v;
  }
  for (int i = tid; i < 2048; i += 512) {
    int bb = i >> 5, tw = i & 31;
    u32 mword = 0;
    for (int j = 0; j < 32; ++j)
      mword |= (x[(size_t)bb * TT + tw * 32 + j] != 0 ? 1u : 0u) << j;
    xmask[bb][tw] = mword;
  }
  float hreg0 = h0[(size_t)b * HH + u0g];
  float hreg1 = h0[(size_t)b * HH + u1g];
  float creg0 = c0[(size_t)b * HH + u0g];
  float creg1 = c0[(size_t)b * HH + u1g];
  __syncthreads();
  if (tid == 0)
    __hip_atomic_store(&flags[w * 16], 1u, __ATOMIC_RELEASE,
                       __HIP_MEMORY_SCOPE_AGENT);

  const size_t OFS1 = (size_t)BB * TT * HH;
  const size_t OFS2 = OFS1 + (size_t)BB * HH;
  u32 mw = 0;

  for (int t = 0; t < TT; ++t) {
    // ---- prefetch (independent of h): xz values + mask word ----
    if ((t & 31) == 0) mw = xmask[b][t >> 5];
    const bool m = (mw >> (t & 31)) & 1;
    float xz00 = bf2f(xz[((size_t)t * GG + 0 * 512 + u0g) * BB + b]);
    float xz01 = bf2f(xz[((size_t)t * GG + 1 * 512 + u0g) * BB + b]);
    float xz02 = bf2f(xz[((size_t)t * GG + 2 * 512 + u0g) * BB + b]);
    float xz03 = bf2f(xz[((size_t)t * GG + 3 * 512 + u0g) * BB + b]);
    float xz10 = bf2f(xz[((size_t)t * GG + 0 * 512 + u1g) * BB + b]);
    float xz11 = bf2f(xz[((size_t)t * GG + 1 * 512 + u1g) * BB + b]);
    float xz12 = bf2f(xz[((size_t)t * GG + 2 * 512 + u1g) * BB + b]);
    float xz13 = bf2f(xz[((size_t)t * GG + 3 * 512 + u1g) * BB + b]);

    // ---- wait for h(t) buffer ready (all 32 WGs) ----
    {
      const u32 tgt = (u32)(t + 1);
      while (true) {
        u32 f = __hip_atomic_load(&flags[(l & 31) * 16], __ATOMIC_ACQUIRE,
                                  __HIP_MEMORY_SCOPE_AGENT);
        if (__all(f >= tgt)) break;
        __builtin_amdgcn_s_sleep(2);
      }
    }

    // ---- load A fragments (coalesced dwordx4 from fragment-ordered hbuf) --
    const bf16x8* abase =
        (const bf16x8*)((t & 1) ? hb1 : hb0) + (size_t)(mt * 16) * 64 + l;
    bf16x8 af[16];
#pragma unroll
    for (int ks = 0; ks < 16; ++ks) af[ks] = abase[(size_t)ks * 64];

    // ---- MFMA: z(64x64) for this wave's 2 tiles ----
    f32x4 acc0 = {0.f, 0.f, 0.f, 0.f}, acc1 = {0.f, 0.f, 0.f, 0.f};
#pragma unroll
    for (int ks = 0; ks < 16; ++ks) {
      acc0 = __builtin_amdgcn_mfma_f32_16x16x32_bf16(af[ks], bfr0[ks], acc0,
                                                     0, 0, 0);
      acc1 = __builtin_amdgcn_mfma_f32_16x16x32_bf16(af[ks], bfr1[ks], acc1,
                                                     0, 0, 0);
    }

    // ---- per tile: 4x4 lane-group transpose, gates, state update ----
#pragma unroll
    for (int ti = 0; ti < 2; ++ti) {
      f32x4 acc = ti ? acc1 : acc0;
      float accLo = (q & 1) ? acc[1] : acc[0];
      float accHi = (q & 1) ? acc[3] : acc[2];
      float sendA = (q & 1) ? acc[0] : acc[1];
      float recvA = __shfl_xor(sendA, 1);
      float sendB = (q & 1) ? acc[2] : acc[3];
      float recvB = __shfl_xor(sendB, 1);
      float k1 = (q & 2) ? accHi : accLo;   // M[q][q]
      float s2A = (q & 2) ? accLo : accHi;
      float r2A = __shfl_xor(s2A, 2);       // M[q^2][q]
      float k2 = (q & 2) ? recvB : recvA;   // M[q^1][q]
      float s2B = (q & 2) ? recvA : recvB;
      float r2B = __shfl_xor(s2B, 2);       // M[q^3][q]
      float p1 = (q & 1) ? k2 : k1;
      float p2 = (q & 1) ? k1 : k2;
      float p3 = (q & 1) ? r2B : r2A;
      float p4 = (q & 1) ? r2A : r2B;
      float W0 = (q & 2) ? p3 : p1;  // gate i
      float W1 = (q & 2) ? p4 : p2;  // gate f
      float W2 = (q & 2) ? p1 : p3;  // gate g
      float W3 = (q & 2) ? p2 : p4;  // gate o
      float z0 = W0 + (ti ? xz10 : xz00);
      float z1 = W1 + (ti ? xz11 : xz01);
      float z2 = W2 + (ti ? xz12 : xz02);
      float z3 = W3 + (ti ? xz13 : xz03);
      float ig = sigm(z0), fg = sigm(z1), gg = tanhfast(z2), og = sigm(z3);
      float cprev = ti ? creg1 : creg0;
      float hprev = ti ? hreg1 : hreg0;
      float cn = fg * cprev + ig * gg;
      float hn = og * tanhfast(cn);
      float ho = m ? hn : hprev;
      float co = m ? cn : cprev;
      if (ti) { creg1 = co; hreg1 = ho; } else { creg0 = co; hreg0 = ho; }
      const int u = ti ? u1g : u0g;
      out[((size_t)b * TT + t) * HH + u] = ho;
      if (t < TT - 1) {
        u16* hdst = (t & 1) ? hb0 : hb1;  // write h(t+1) into other buffer
        int ln = (b & 15) | (((u >> 3) & 3) << 4);
        hdst[(size_t)(((b >> 4) * 16 + (u >> 5)) * 64 + ln) * 8 + (u & 7)] =
            f2bf(ho);
      } else {
        out[OFS1 + (size_t)b * HH + u] = ho;
        out[OFS2 + (size_t)b * HH + u] = co;
      }
    }

    // ---- publish h(t+1) ----
    if (t < TT - 1) {
      __syncthreads();  // drains each wave's vmcnt before barrier
      if (tid == 0)
        __hip_atomic_store(&flags[w * 16], (u32)(t + 2), __ATOMIC_RELEASE,
                           __HIP_MEMORY_SCOPE_AGENT);
    }
  }
}

// ---------------------------------------------------------------------------
extern "C" void kernel_launch(void* const* d_in, const int* in_sizes, int n_in,
                              void* d_out, int out_size, void* d_ws,
                              size_t ws_size, hipStream_t stream) {
  const int* x = (const int*)d_in[0];
  const float* h0 = (const float*)d_in[1];
  const float* c0 = (const float*)d_in[2];
  const float* emb = (const float*)d_in[3];
  const float* Wk = (const float*)d_in[4];
  const float* rec = (const float*)d_in[5];
  const float* bias = (const float*)d_in[6];
  float* out = (float*)d_out;
  char* ws = (char*)d_ws;

  const size_t xz_bytes = (size_t)TT * GG * BB * 2;  // 256 MiB bf16
  u16* xz = (u16*)ws;
  u16* hb0 = (u16*)(ws + xz_bytes);            // 64 KiB (A-fragment order)
  u16* hb1 = (u16*)(ws + xz_bytes + 65536);    // 64 KiB
  u32* flags = (u32*)(ws + xz_bytes + 131072);
  if (ws_size < xz_bytes + 131072 + 8192) return;

  hipMemsetAsync(flags, 0, 8192, stream);

  dim3 g1(TT, 32);
  xz_gemm<<<g1, 256, 0, stream>>>(x, emb, Wk, bias, xz);
  lstm_scan2<<<NWG, 512, 0, stream>>>(x, h0, c0, rec, xz, out, hb0, hb1,
                                      flags);
}